// Round 5
// baseline (192.430 us; speedup 1.0000x reference)
//
#include <hip/hip_runtime.h>
#include <hip/hip_bf16.h>

#define BATCH 4096
#define DIM 4096
#define NSPLIT 64
#define ROWS_PB 64
#define NCHUNK 64            // BATCH / ROWS_PB
#define BN_EPS 1e-3f

typedef __attribute__((ext_vector_type(8))) short bf16x8;
typedef __attribute__((ext_vector_type(4))) float f32x4;

__device__ inline unsigned short f2bf(float f) {
    union { float f; unsigned int u; } c; c.f = f;
    unsigned int u = c.u;
    u += 0x7FFFu + ((u >> 16) & 1u);   // round-to-nearest-even
    return (unsigned short)(u >> 16);
}

// Shared staging: X tile 64x64 -> bf16 LDS, W_s^T -> bf16 LDS, bias.
// 64-row tiles, 4096 blocks total: ~7 blocks/CU for latency overlap.
__device__ inline void stage(const float* __restrict__ x,
                             const float* __restrict__ w,
                             int s, int r0, int t,
                             unsigned short xs[64][72],
                             unsigned short wt[64][72])
{
    #pragma unroll
    for (int it = 0; it < 4; it++) {
        int i = t + it * 256;
        int row = i >> 4, c4 = i & 15;
        float4 v = *(const float4*)(x + (size_t)(r0 + row) * DIM + s*64 + c4*4);
        ushort4 u;
        u.x = f2bf(v.x); u.y = f2bf(v.y); u.z = f2bf(v.z); u.w = f2bf(v.w);
        *(ushort4*)&xs[row][c4*4] = u;
    }
    #pragma unroll
    for (int it = 0; it < 4; it++) {
        int i = t + it * 256;
        int k = i >> 4, c4 = i & 15;
        float4 v = *(const float4*)(w + (size_t)(s*64 + k) * DIM + s*64 + c4*4);
        wt[c4*4 + 0][k] = f2bf(v.x);
        wt[c4*4 + 1][k] = f2bf(v.y);
        wt[c4*4 + 2][k] = f2bf(v.z);
        wt[c4*4 + 3][k] = f2bf(v.w);
    }
}

// Per-wave GEMM on a 16x64 row strip: 8 MFMAs, acc[ct] 16 VGPRs.
__device__ inline void gemm16x64(const unsigned short xs[64][72],
                                 const unsigned short wt[64][72],
                                 const float* bcol,
                                 int wave, int quad, int l16, f32x4 acc[4])
{
    #pragma unroll
    for (int ct = 0; ct < 4; ct++) {
        float b = bcol[ct*16 + l16];
        acc[ct] = (f32x4){b, b, b, b};
    }
    bf16x8 af[2], bf[4][2];
    #pragma unroll
    for (int kk = 0; kk < 2; kk++)
        af[kk] = *(const bf16x8*)&xs[wave*16 + l16][kk*32 + quad*8];
    #pragma unroll
    for (int ct = 0; ct < 4; ct++)
        #pragma unroll
        for (int kk = 0; kk < 2; kk++)
            bf[ct][kk] = *(const bf16x8*)&wt[ct*16 + l16][kk*32 + quad*8];
    #pragma unroll
    for (int kk = 0; kk < 2; kk++)
        #pragma unroll
        for (int ct = 0; ct < 4; ct++)
            acc[ct] = __builtin_amdgcn_mfma_f32_16x16x32_bf16(
                af[kk], bf[ct][kk], acc[ct], 0, 0, 0);
}

// Pass 1: GEMM + per-block column sum/sumsq partials (plain stores, 512 B/block).
__global__ __launch_bounds__(256) void stats_pass(
    const float* __restrict__ x, const float* __restrict__ w,
    const float* __restrict__ bias, float* __restrict__ part)
{
    __shared__ unsigned short xs[64][72];
    __shared__ unsigned short wt[64][72];
    __shared__ float bcol[64];
    __shared__ float red1[4][64], red2[4][64];

    const int s  = blockIdx.y;
    const int r0 = blockIdx.x * ROWS_PB;
    const int t  = threadIdx.x;
    const int lane = t & 63, wave = t >> 6;
    const int quad = lane >> 4, l16 = lane & 15;

    if (t < 64) bcol[t] = bias[s*64 + t];
    stage(x, w, s, r0, t, xs, wt);
    __syncthreads();

    f32x4 acc[4];
    gemm16x64(xs, wt, bcol, wave, quad, l16, acc);

    float s1[4], s2[4];
    #pragma unroll
    for (int ct = 0; ct < 4; ct++) {
        s1[ct] = 0.f; s2[ct] = 0.f;
        #pragma unroll
        for (int r = 0; r < 4; r++) {
            float v = acc[ct][r];
            s1[ct] += v; s2[ct] += v * v;
        }
        float a = s1[ct], b = s2[ct];
        a += __shfl_xor(a, 16); b += __shfl_xor(b, 16);
        a += __shfl_xor(a, 32); b += __shfl_xor(b, 32);
        if (quad == 0) {
            red1[wave][ct*16 + l16] = a;
            red2[wave][ct*16 + l16] = b;
        }
    }
    __syncthreads();
    if (t < 64) {
        float a = red1[0][t] + red1[1][t] + red1[2][t] + red1[3][t];
        float b = red2[0][t] + red2[1][t] + red2[2][t] + red2[3][t];
        size_t base = (size_t)(s * NCHUNK + blockIdx.x) * 128;
        part[base + t]      = a;
        part[base + 64 + t] = b;
    }
}

// Pass 2: GEMM again + per-block stats fold + BN + ReLU + fp32 store.
__global__ __launch_bounds__(256) void main_pass(
    const float* __restrict__ x, const float* __restrict__ w,
    const float* __restrict__ bias, const float* __restrict__ gamma,
    const float* __restrict__ beta, const float* __restrict__ part,
    float* __restrict__ out)
{
    __shared__ unsigned short xs[64][72];
    __shared__ unsigned short wt[64][72];
    __shared__ float bcol[64];
    __shared__ float scol[64], shcol[64];

    const int s  = blockIdx.y;
    const int r0 = blockIdx.x * ROWS_PB;
    const int t  = threadIdx.x;
    const int lane = t & 63, wave = t >> 6;
    const int quad = lane >> 4, l16 = lane & 15;

    if (t < 64) bcol[t] = bias[s*64 + t];
    stage(x, w, s, r0, t, xs, wt);

    // fold this split's 64 partials -> scale/shift (redundant per block; L2 reads)
    if (t < 64) {
        float a = 0.f, b = 0.f;
        #pragma unroll 8
        for (int p = 0; p < NCHUNK; p++) {
            size_t base = (size_t)(s * NCHUNK + p) * 128;
            a += part[base + t];
            b += part[base + 64 + t];
        }
        float mean = a * (1.f / BATCH);
        float var  = b * (1.f / BATCH) - mean * mean;
        float rstd = rsqrtf(var + BN_EPS);
        float sc = gamma[s*64 + t] * rstd;
        scol[t]  = sc;
        shcol[t] = beta[s*64 + t] - mean * sc;
    }
    __syncthreads();

    f32x4 acc[4];
    gemm16x64(xs, wt, bcol, wave, quad, l16, acc);

    #pragma unroll
    for (int ct = 0; ct < 4; ct++) {
        int col = ct*16 + l16;
        float sc = scol[col], sh = shcol[col];
        #pragma unroll
        for (int r = 0; r < 4; r++) {
            float v = fmaxf(fmaf(acc[ct][r], sc, sh), 0.f);
            int row = r0 + wave*16 + quad*4 + r;
            out[(size_t)row * DIM + s*64 + col] = v;
        }
    }
}

extern "C" void kernel_launch(void* const* d_in, const int* in_sizes, int n_in,
                              void* d_out, int out_size, void* d_ws, size_t ws_size,
                              hipStream_t stream) {
    const float* x     = (const float*)d_in[0];
    const float* w     = (const float*)d_in[1];
    const float* bias  = (const float*)d_in[2];
    const float* gamma = (const float*)d_in[3];
    const float* beta  = (const float*)d_in[4];
    float* out  = (float*)d_out;
    float* part = (float*)d_ws;    // 4096 * 128 floats = 2 MB, fully written by pass 1

    stats_pass<<<dim3(NCHUNK, NSPLIT), 256, 0, stream>>>(x, w, bias, part);
    main_pass<<<dim3(NCHUNK, NSPLIT), 256, 0, stream>>>(x, w, bias, gamma, beta,
                                                        part, out);
}